// Round 4
// baseline (107.348 us; speedup 1.0000x reference)
//
#include <hip/hip_runtime.h>
#include <hip/hip_bf16.h>

// PosteriorRotationN: B=8,T=120,N=24,D=48,C=1128,DE=256
// k0w: Wkv f32 -> bf16 (24 KB, L2-resident)
// k1 : kv[bn][c][d] = ctx·Wkv + bkv   (bf16 MFMA; A direct-from-global, B from global-L2, no K-loop barriers)
// k2 : sp = x·kv^T -> g=0.1*tanh(sp) -> gather matvec -> out = x + dx

constexpr int Bc = 8, Tc = 120, Nc = 24, Dc = 48, Cc = 1128, DEc = 256;
constexpr int BNc = Bc * Nc;        // 192
constexpr int KVP = 64;             // kv row padded to 64 (zeros at 48..63)

using short8 = __attribute__((ext_vector_type(8))) short;
using f32x4  = __attribute__((ext_vector_type(4))) float;

__device__ __forceinline__ ushort f2b(float f) {
    union { float f; unsigned u; } v; v.f = f;
    unsigned r = (v.u + 0x7fffu + ((v.u >> 16) & 1u)) >> 16;
    return (ushort)r;
}
__device__ __forceinline__ short bcast(float f) {
    return (short)__bfloat16_as_ushort(__float2bfloat16(f));
}
__device__ __forceinline__ short8 pack8(const float4& a, const float4& b) {
    short8 r;
    r[0] = bcast(a.x); r[1] = bcast(a.y); r[2] = bcast(a.z); r[3] = bcast(a.w);
    r[4] = bcast(b.x); r[5] = bcast(b.y); r[6] = bcast(b.z); r[7] = bcast(b.w);
    return r;
}

// ---------------- K0w: Wkv f32 -> bf16 ----------------
__global__ void k0w(const float* __restrict__ Wkv, ushort* __restrict__ wkvb) {
    int i = blockIdx.x * 256 + threadIdx.x;          // 3072 threads, 4 elems each
    float4 w = *reinterpret_cast<const float4*>(Wkv + i * 4);
    ushort4 u;
    u.x = (ushort)bcast(w.x); u.y = (ushort)bcast(w.y);
    u.z = (ushort)bcast(w.z); u.w = (ushort)bcast(w.w);
    *reinterpret_cast<ushort4*>(wkvb + i * 4) = u;
}

// ---------------- K1: kv GEMM, bf16 MFMA, A and B direct-from-global ----------------
// grid (192 bn, 9 c-blocks), 256 thr = 4 independent waves, each owns 32 c-rows.
constexpr int STs = 72;   // transpose-staging stride (bf16 elems), 144 B, 16B-aligned
__global__ __launch_bounds__(256, 4) void k1_kv(const float* __restrict__ ctx,
                                                const ushort* __restrict__ wkvb,
                                                const float* __restrict__ bkv,
                                                ushort* __restrict__ kvb) {
    __shared__ ushort sT[4][32 * STs];       // 18432 B, per-wave output transpose tile
    const int bn = blockIdx.x, c0 = blockIdx.y * 128;
    const int b = bn / Nc, n = bn % Nc;
    const int tid = threadIdx.x, wave = tid >> 6, lane = tid & 63;
    const int tr = lane & 15, kg = lane >> 4;
    const float* ctxb = ctx + ((size_t)b * Cc * Nc + n) * DEc;

    // per-lane A rows (clamped; results for c>=Cc discarded at store)
    const float* arow[2];
    #pragma unroll
    for (int mf = 0; mf < 2; ++mf) {
        int c = c0 + wave * 32 + mf * 16 + tr;
        arow[mf] = ctxb + (size_t)(c < Cc ? c : Cc - 1) * (Nc * DEc);
    }

    f32x4 acc[2][3];
    #pragma unroll
    for (int mf = 0; mf < 2; ++mf)
        #pragma unroll
        for (int nf = 0; nf < 3; ++nf) acc[mf][nf] = (f32x4){0.f, 0.f, 0.f, 0.f};

    #pragma unroll
    for (int ks = 0; ks < 8; ++ks) {           // K=256 in 8 steps of 32, no barriers
        const int e0 = ks * 32 + kg * 8;
        short8 af[2];
        #pragma unroll
        for (int mf = 0; mf < 2; ++mf) {
            float4 a0 = *reinterpret_cast<const float4*>(arow[mf] + e0);
            float4 a1 = *reinterpret_cast<const float4*>(arow[mf] + e0 + 4);
            af[mf] = pack8(a0, a1);
        }
        short8 bf[3];
        #pragma unroll
        for (int nf = 0; nf < 3; ++nf)
            bf[nf] = *reinterpret_cast<const short8*>(&wkvb[(nf * 16 + tr) * DEc + e0]);
        #pragma unroll
        for (int mf = 0; mf < 2; ++mf)
            #pragma unroll
            for (int nf = 0; nf < 3; ++nf)
                acc[mf][nf] = __builtin_amdgcn_mfma_f32_16x16x32_bf16(af[mf], bf[nf], acc[mf][nf], 0, 0, 0);
    }

    // epilogue: +bias, transpose through per-wave LDS tile, coalesced stores
    float bias[3];
    #pragma unroll
    for (int nf = 0; nf < 3; ++nf) bias[nf] = bkv[nf * 16 + tr];
    #pragma unroll
    for (int mf = 0; mf < 2; ++mf)
        #pragma unroll
        for (int nf = 0; nf < 3; ++nf)
            #pragma unroll
            for (int r = 0; r < 4; ++r)
                sT[wave][(mf * 16 + kg * 4 + r) * STs + nf * 16 + tr] = f2b(acc[mf][nf][r] + bias[nf]);
    {   // zero pad cols 48..63 (16 bf16 = two 16B chunks per row; 2 lanes/row)
        int row = lane >> 1, half = lane & 1;
        short8 z = (short8){0, 0, 0, 0, 0, 0, 0, 0};
        *reinterpret_cast<short8*>(&sT[wave][row * STs + 48 + half * 8]) = z;
    }
    __syncthreads();
    #pragma unroll
    for (int p = 0; p < 4; ++p) {
        int row = p * 8 + (lane >> 3), colv = (lane & 7) * 8;
        short8 v = *reinterpret_cast<const short8*>(&sT[wave][row * STs + colv]);
        int c = c0 + wave * 32 + row;
        if (c < Cc)
            *reinterpret_cast<short8*>(&kvb[((size_t)bn * Cc + c) * KVP + colv]) = v;
    }
}

// ---------------- K2: sp MFMA + tanh + gather matvec (unchanged) ----------------
// grid 1536 = 192 bn x 8 t-tiles(16), XCD-swizzled so a bn's tiles share an XCD L2.
constexpr int SGs = 1136;  // sG f32 stride
__global__ __launch_bounds__(256) void k2_fused(const float* __restrict__ x,
                                                const ushort* __restrict__ kvb,
                                                float* __restrict__ out) {
    __shared__ float  sG[16 * SGs];    // 72704 B
    __shared__ float  sXf[16 * 52];    // 3328 B
    __shared__ ushort sXb[16 * 72];    // 2304 B (K-padded to 64 w/ zeros)
    const int L = blockIdx.x;
    const int bn = (L & 7) + 8 * (L >> 6);   // bn%8 == XCD slot
    const int tt = (L >> 3) & 7;
    const int b = bn / Nc, n = bn % Nc, t0 = tt * 16;
    const int tid = threadIdx.x, wave = tid >> 6, lane = tid & 63;
    const int tr = lane & 15, kg = lane >> 4;

    for (int l = tid; l < 16 * 72 / 4; l += 256)
        *reinterpret_cast<ushort4*>(&sXb[l * 4]) = make_ushort4(0, 0, 0, 0);
    __syncthreads();
    if (tid < 192) {
        int t = tid / 12, dv = (tid % 12) * 4, tg = t0 + t;
        float4 v = make_float4(0.f, 0.f, 0.f, 0.f);
        if (tg < Tc) v = *reinterpret_cast<const float4*>(x + (((size_t)b * Tc + tg) * Nc + n) * Dc + dv);
        *reinterpret_cast<float4*>(&sXf[t * 52 + dv]) = v;
        *reinterpret_cast<ushort4*>(&sXb[t * 72 + dv]) = make_ushort4(f2b(v.x), f2b(v.y), f2b(v.z), f2b(v.w));
    }
    __syncthreads();
    // A-frags (t=lane&15, k contiguous-8) hoisted to regs
    const short8 af0 = *reinterpret_cast<const short8*>(&sXb[tr * 72 + kg * 8]);
    const short8 af1 = *reinterpret_cast<const short8*>(&sXb[tr * 72 + 32 + kg * 8]);
    const ushort* kvbn = kvb + (size_t)bn * Cc * KVP;
    // phase A: 71 c-frags over 4 waves; B-frags straight from global (L2)
    for (int nf = wave; nf < 71; nf += 4) {
        int c = nf * 16 + tr;
        int ce = c < Cc ? c : Cc - 1;
        short8 b0 = *reinterpret_cast<const short8*>(&kvbn[(size_t)ce * KVP + kg * 8]);
        short8 b1 = *reinterpret_cast<const short8*>(&kvbn[(size_t)ce * KVP + 32 + kg * 8]);
        f32x4 a = (f32x4){0.f, 0.f, 0.f, 0.f};
        a = __builtin_amdgcn_mfma_f32_16x16x32_bf16(af0, b0, a, 0, 0, 0);
        a = __builtin_amdgcn_mfma_f32_16x16x32_bf16(af1, b1, a, 0, 0, 0);
        #pragma unroll
        for (int r = 0; r < 4; ++r) {   // C/D: col=lane&15 (=c), row=kg*4+r (=t)
            float g = 0.1f - 0.2f * __builtin_amdgcn_rcpf(__expf(2.0f * a[r]) + 1.0f);
            sG[(kg * 4 + r) * SGs + c] = g;
        }
    }
    __syncthreads();
    // phase B: thread owns 3 (t,e) pairs; 48-iter gather, no atomics
    int ea[3], ta[3], tea[3];
    float dxa[3];
    #pragma unroll
    for (int p = 0; p < 3; ++p) {
        int idx = tid + p * 256;
        ta[p] = idx / 48; ea[p] = idx % 48;
        tea[p] = ea[p] * (ea[p] - 1) / 2;
        dxa[p] = 0.f;
    }
    int td = 0;
    #pragma unroll 4
    for (int d = 0; d < 48; ++d) {
        #pragma unroll
        for (int p = 0; p < 3; ++p) {
            bool gt = d > ea[p];
            int c = gt ? (td + ea[p]) : (tea[p] + d);
            float gv = sG[ta[p] * SGs + c];
            float xv = sXf[ta[p] * 52 + d];
            float m = gt ? xv : -xv;
            if (d == ea[p]) m = 0.f;
            dxa[p] = fmaf(m, gv, dxa[p]);
        }
        td += d;
    }
    #pragma unroll
    for (int p = 0; p < 3; ++p) {
        int tg = t0 + ta[p];
        if (tg < Tc)
            out[(((size_t)b * Tc + tg) * Nc + n) * Dc + ea[p]] = sXf[ta[p] * 52 + ea[p]] + dxa[p];
    }
}

extern "C" void kernel_launch(void* const* d_in, const int* in_sizes, int n_in,
                              void* d_out, int out_size, void* d_ws, size_t ws_size,
                              hipStream_t stream) {
    (void)in_sizes; (void)n_in; (void)out_size; (void)ws_size;
    const float* x   = (const float*)d_in[0];
    const float* ctx = (const float*)d_in[1];
    const float* Wkv = (const float*)d_in[2];
    const float* bkv = (const float*)d_in[3];
    float* out   = (float*)d_out;
    ushort* wkvb = (ushort*)d_ws;                          // 48*256*2 = 24 KB
    ushort* kvb  = (ushort*)((char*)d_ws + 32768);         // 192*1128*64*2 = 27.7 MB

    k0w<<<dim3(12), dim3(256), 0, stream>>>(Wkv, wkvb);
    k1_kv<<<dim3(BNc, 9), dim3(256), 0, stream>>>(ctx, wkvb, bkv, kvb);
    k2_fused<<<dim3(BNc * 8), dim3(256), 0, stream>>>(x, kvb, out);
}

// Round 5
// 97.577 us; speedup vs baseline: 1.1001x; 1.1001x over previous
//
#include <hip/hip_runtime.h>
#include <hip/hip_bf16.h>

// PosteriorRotationN: B=8,T=120,N=24,D=48,C=1128,DE=256
// k0w: Wkv f32 -> bf16 (24 KB, L2-resident)
// k1 : kv[bn][c][d] = ctx·Wkv + bkv   (bf16 MFMA, swapped operands: A=Wkv(M=d), B=ctx(N=c);
//      C/D layout gives 4 contiguous d per lane -> direct ushort4 stores, no transpose LDS)
// k2 : sp = x·kv^T -> g=0.1*tanh(sp) -> gather matvec -> out = x + dx

constexpr int Bc = 8, Tc = 120, Nc = 24, Dc = 48, Cc = 1128, DEc = 256;
constexpr int BNc = Bc * Nc;        // 192
constexpr int KVP = 64;             // kv row padded to 64 (zeros at 48..63)

using short8 = __attribute__((ext_vector_type(8))) short;
using f32x4  = __attribute__((ext_vector_type(4))) float;

__device__ __forceinline__ ushort f2b(float f) {
    union { float f; unsigned u; } v; v.f = f;
    unsigned r = (v.u + 0x7fffu + ((v.u >> 16) & 1u)) >> 16;
    return (ushort)r;
}
__device__ __forceinline__ short bcast(float f) {
    return (short)__bfloat16_as_ushort(__float2bfloat16(f));
}
__device__ __forceinline__ short8 pack8(const float4& a, const float4& b) {
    short8 r;
    r[0] = bcast(a.x); r[1] = bcast(a.y); r[2] = bcast(a.z); r[3] = bcast(a.w);
    r[4] = bcast(b.x); r[5] = bcast(b.y); r[6] = bcast(b.z); r[7] = bcast(b.w);
    return r;
}

// ---------------- K0w: Wkv f32 -> bf16 ----------------
__global__ void k0w(const float* __restrict__ Wkv, ushort* __restrict__ wkvb) {
    int i = blockIdx.x * 256 + threadIdx.x;          // 3072 threads, 4 elems each
    float4 w = *reinterpret_cast<const float4*>(Wkv + i * 4);
    ushort4 u;
    u.x = (ushort)bcast(w.x); u.y = (ushort)bcast(w.y);
    u.z = (ushort)bcast(w.z); u.w = (ushort)bcast(w.w);
    *reinterpret_cast<ushort4*>(wkvb + i * 4) = u;
}

// ---------------- K1: kv GEMM, bf16 MFMA, swapped operands ----------------
// grid (192 bn, 9 c-blocks), 256 thr = 4 waves, each owns 32 c-cols.
constexpr int SWs = 264;  // Wkv LDS stride (bf16 elems): 528 B row
__global__ __launch_bounds__(256) void k1_kv(const float* __restrict__ ctx,
                                             const ushort* __restrict__ wkvb,
                                             const float* __restrict__ bkv,
                                             ushort* __restrict__ kvb) {
    __shared__ ushort sW[Dc * SWs];          // 25344 B, full K=256 of Wkv (bf16)
    const int bn = blockIdx.x, c0 = blockIdx.y * 128;
    const int b = bn / Nc, n = bn % Nc;
    const int tid = threadIdx.x, wave = tid >> 6, lane = tid & 63;
    const int tr = lane & 15, kg = lane >> 4;
    const float* ctxb = ctx + ((size_t)b * Cc * Nc + n) * DEc;

    // stage Wkv bf16 -> LDS (16B chunks), one barrier total
    for (int l = tid; l < Dc * 32; l += 256) {
        int d = l >> 5, e = (l & 31) << 3;
        *reinterpret_cast<short8*>(&sW[d * SWs + e]) =
            *reinterpret_cast<const short8*>(&wkvb[d * DEc + e]);
    }

    // per-lane ctx rows (B operand: col c = base + tr), clamped
    const float* crow[2];
    #pragma unroll
    for (int cn = 0; cn < 2; ++cn) {
        int c = c0 + wave * 32 + cn * 16 + tr;
        crow[cn] = ctxb + (size_t)(c < Cc ? c : Cc - 1) * (Nc * DEc);
    }

    f32x4 acc[3][2];
    #pragma unroll
    for (int mf = 0; mf < 3; ++mf)
        #pragma unroll
        for (int cn = 0; cn < 2; ++cn) acc[mf][cn] = (f32x4){0.f, 0.f, 0.f, 0.f};

    __syncthreads();

    #pragma unroll
    for (int ks = 0; ks < 8; ++ks) {           // K=256 in 8 steps of 32, no barriers
        const int e0 = ks * 32 + kg * 8;
        short8 bfrag[2];
        #pragma unroll
        for (int cn = 0; cn < 2; ++cn) {
            float4 a0 = *reinterpret_cast<const float4*>(crow[cn] + e0);
            float4 a1 = *reinterpret_cast<const float4*>(crow[cn] + e0 + 4);
            bfrag[cn] = pack8(a0, a1);
        }
        short8 afrag[3];
        #pragma unroll
        for (int mf = 0; mf < 3; ++mf)
            afrag[mf] = *reinterpret_cast<const short8*>(&sW[(mf * 16 + tr) * SWs + e0]);
        #pragma unroll
        for (int mf = 0; mf < 3; ++mf)
            #pragma unroll
            for (int cn = 0; cn < 2; ++cn)
                acc[mf][cn] = __builtin_amdgcn_mfma_f32_16x16x32_bf16(afrag[mf], bfrag[cn], acc[mf][cn], 0, 0, 0);
    }

    // epilogue: +bias, direct ushort4 stores (d = mf*16 + kg*4 + r contiguous in r)
    float4 bias[3];
    #pragma unroll
    for (int mf = 0; mf < 3; ++mf)
        bias[mf] = *reinterpret_cast<const float4*>(bkv + mf * 16 + kg * 4);
    #pragma unroll
    for (int cn = 0; cn < 2; ++cn) {
        int c = c0 + wave * 32 + cn * 16 + tr;
        if (c < Cc) {
            ushort* dst = kvb + ((size_t)bn * Cc + c) * KVP;
            #pragma unroll
            for (int mf = 0; mf < 3; ++mf) {
                ushort4 u;
                u.x = f2b(acc[mf][cn][0] + bias[mf].x);
                u.y = f2b(acc[mf][cn][1] + bias[mf].y);
                u.z = f2b(acc[mf][cn][2] + bias[mf].z);
                u.w = f2b(acc[mf][cn][3] + bias[mf].w);
                *reinterpret_cast<ushort4*>(dst + mf * 16 + kg * 4) = u;
            }
        }
    }
    {   // zero pad cols 48..63 (32 B per row; 2 lanes/row, 16 B each)
        int row = lane >> 1, half = lane & 1;
        int c = c0 + wave * 32 + row;
        if (c < Cc) {
            short8 z = (short8){0, 0, 0, 0, 0, 0, 0, 0};
            *reinterpret_cast<short8*>(&kvb[((size_t)bn * Cc + c) * KVP + 48 + half * 8]) = z;
        }
    }
}

// ---------------- K2: sp MFMA + tanh + gather matvec (unchanged) ----------------
// grid 1536 = 192 bn x 8 t-tiles(16), XCD-swizzled so a bn's tiles share an XCD L2.
constexpr int SGs = 1136;  // sG f32 stride
__global__ __launch_bounds__(256) void k2_fused(const float* __restrict__ x,
                                                const ushort* __restrict__ kvb,
                                                float* __restrict__ out) {
    __shared__ float  sG[16 * SGs];    // 72704 B
    __shared__ float  sXf[16 * 52];    // 3328 B
    __shared__ ushort sXb[16 * 72];    // 2304 B (K-padded to 64 w/ zeros)
    const int L = blockIdx.x;
    const int bn = (L & 7) + 8 * (L >> 6);   // bn%8 == XCD slot
    const int tt = (L >> 3) & 7;
    const int b = bn / Nc, n = bn % Nc, t0 = tt * 16;
    const int tid = threadIdx.x, wave = tid >> 6, lane = tid & 63;
    const int tr = lane & 15, kg = lane >> 4;

    for (int l = tid; l < 16 * 72 / 4; l += 256)
        *reinterpret_cast<ushort4*>(&sXb[l * 4]) = make_ushort4(0, 0, 0, 0);
    __syncthreads();
    if (tid < 192) {
        int t = tid / 12, dv = (tid % 12) * 4, tg = t0 + t;
        float4 v = make_float4(0.f, 0.f, 0.f, 0.f);
        if (tg < Tc) v = *reinterpret_cast<const float4*>(x + (((size_t)b * Tc + tg) * Nc + n) * Dc + dv);
        *reinterpret_cast<float4*>(&sXf[t * 52 + dv]) = v;
        *reinterpret_cast<ushort4*>(&sXb[t * 72 + dv]) = make_ushort4(f2b(v.x), f2b(v.y), f2b(v.z), f2b(v.w));
    }
    __syncthreads();
    // A-frags (t=lane&15, k contiguous-8) hoisted to regs
    const short8 af0 = *reinterpret_cast<const short8*>(&sXb[tr * 72 + kg * 8]);
    const short8 af1 = *reinterpret_cast<const short8*>(&sXb[tr * 72 + 32 + kg * 8]);
    const ushort* kvbn = kvb + (size_t)bn * Cc * KVP;
    // phase A: 71 c-frags over 4 waves; B-frags straight from global (L2)
    for (int nf = wave; nf < 71; nf += 4) {
        int c = nf * 16 + tr;
        int ce = c < Cc ? c : Cc - 1;
        short8 b0 = *reinterpret_cast<const short8*>(&kvbn[(size_t)ce * KVP + kg * 8]);
        short8 b1 = *reinterpret_cast<const short8*>(&kvbn[(size_t)ce * KVP + 32 + kg * 8]);
        f32x4 a = (f32x4){0.f, 0.f, 0.f, 0.f};
        a = __builtin_amdgcn_mfma_f32_16x16x32_bf16(af0, b0, a, 0, 0, 0);
        a = __builtin_amdgcn_mfma_f32_16x16x32_bf16(af1, b1, a, 0, 0, 0);
        #pragma unroll
        for (int r = 0; r < 4; ++r) {   // C/D: col=lane&15 (=c), row=kg*4+r (=t)
            float g = 0.1f - 0.2f * __builtin_amdgcn_rcpf(__expf(2.0f * a[r]) + 1.0f);
            sG[(kg * 4 + r) * SGs + c] = g;
        }
    }
    __syncthreads();
    // phase B: thread owns 3 (t,e) pairs; 48-iter gather, no atomics
    int ea[3], ta[3], tea[3];
    float dxa[3];
    #pragma unroll
    for (int p = 0; p < 3; ++p) {
        int idx = tid + p * 256;
        ta[p] = idx / 48; ea[p] = idx % 48;
        tea[p] = ea[p] * (ea[p] - 1) / 2;
        dxa[p] = 0.f;
    }
    int td = 0;
    #pragma unroll 4
    for (int d = 0; d < 48; ++d) {
        #pragma unroll
        for (int p = 0; p < 3; ++p) {
            bool gt = d > ea[p];
            int c = gt ? (td + ea[p]) : (tea[p] + d);
            float gv = sG[ta[p] * SGs + c];
            float xv = sXf[ta[p] * 52 + d];
            float m = gt ? xv : -xv;
            if (d == ea[p]) m = 0.f;
            dxa[p] = fmaf(m, gv, dxa[p]);
        }
        td += d;
    }
    #pragma unroll
    for (int p = 0; p < 3; ++p) {
        int tg = t0 + ta[p];
        if (tg < Tc)
            out[(((size_t)b * Tc + tg) * Nc + n) * Dc + ea[p]] = sXf[ta[p] * 52 + ea[p]] + dxa[p];
    }
}

extern "C" void kernel_launch(void* const* d_in, const int* in_sizes, int n_in,
                              void* d_out, int out_size, void* d_ws, size_t ws_size,
                              hipStream_t stream) {
    (void)in_sizes; (void)n_in; (void)out_size; (void)ws_size;
    const float* x   = (const float*)d_in[0];
    const float* ctx = (const float*)d_in[1];
    const float* Wkv = (const float*)d_in[2];
    const float* bkv = (const float*)d_in[3];
    float* out   = (float*)d_out;
    ushort* wkvb = (ushort*)d_ws;                          // 48*256*2 = 24 KB
    ushort* kvb  = (ushort*)((char*)d_ws + 32768);         // 192*1128*64*2 = 27.7 MB

    k0w<<<dim3(12), dim3(256), 0, stream>>>(Wkv, wkvb);
    k1_kv<<<dim3(BNc, 9), dim3(256), 0, stream>>>(ctx, wkvb, bkv, kvb);
    k2_fused<<<dim3(BNc * 8), dim3(256), 0, stream>>>(x, kvb, out);
}